// Round 13
// baseline (132.938 us; speedup 1.0000x reference)
//
#include <hip/hip_runtime.h>
#include <hip/hip_fp16.h>
#include <math.h>

// CAM_43344809951340: per-sample symmetric outer-product tanh attention.
// H_row[r] = 0.1*relu( sum_j tanh(x_r * av_j / 8) * W_{row_r}[j] + x_r )
//
// Validated diagonal walk (R5-R12, absmax ~2e-3): step k=31..1, lane r
// computes the pair (r, j=(r+k)&63) once:
//   own-row:  p * wo_k   (wo_k = W_{sel(r)}[(r+k)&63])
//   mirror:   t = ror1(fma(p, wd_k, t))  (wd_k = W_{sel(j)}[r]);
//             WAVE_ROR1 (0x13C) moves values toward higher lanes, so a
//             deposit at step k lands at lane r+k after its k rotations.
//   traveling operand a = RAW x_j (scales folded into per-sample consts).
// Weights packed __half2 (8 KB); LDS total 16.4 KB -> 8 blocks/CU.
// __launch_bounds__(256,4): 128-VGPR budget (R7/R9/R11: tighter caps
// spill the whole loop to scratch; occupancy follows ACTUAL VGPR=~60).
//
// R13 change (from R12 counters): DS pipe saturated (97 DS instrs/pair
// x 5.8cy + 9.95M deterministic gather-conflict cy ~= 149k cy/CU ~= wall;
// VALU only ~40% real). Split the two samples across pipes:
//   sample A: tanh via 2048-pt LDS LUT        (DS pipe, R10/R12 path)
//   sample B: tanh = 1 - 2/(1+exp2(C*x*a))    (trans pipe, R6 path)
// DS 97->66 instrs/pair, conflicts halve; trans pipe absorbs B-side.

__device__ __forceinline__ float wave_ror1_f32(float v) {
    // D[i] = S[(i-1) & 63] — values move toward higher lanes
    return __int_as_float(__builtin_amdgcn_update_dpp(
        __float_as_int(v), __float_as_int(v), 0x13C, 0xF, 0xF, false));
}

// tanh(xA * a / 8) by nearest lookup; xs32 = 32*xA so idx = 256*u + 1024.
__device__ __forceinline__ float tanh_lut(const float* __restrict__ tb,
                                          float xs32, float a) {
    float idxf = fmaf(xs32, a, 1024.5f);               // +0.5: round via trunc
    idxf = __builtin_amdgcn_fmed3f(idxf, 0.0f, 2047.0f);
    return tb[(int)idxf];
}

// tanh(xB * a / 8) via trans pipe; xc = C*xB, C = 2*(1/8)*log2(e).
__device__ __forceinline__ float tanh_sig(float xc, float a) {
    const float s = __builtin_amdgcn_rcpf(1.0f + __builtin_amdgcn_exp2f(xc * a));
    return fmaf(-2.0f, s, 1.0f);
}

__global__ __launch_bounds__(256, 4) void cam_kernel(
    const float* __restrict__ f1,
    const float* __restrict__ f2,
    const float* __restrict__ Wca,
    const float* __restrict__ Wcv,
    float* __restrict__ out,
    int B)
{
    constexpr float C = 0.3606737602222409f;           // 2*(1/8)*log2(e)

    // s_Qh[k][ln] = half2{ W_{sel(ln)}[(ln+k)&63], W_{half((ln+k)&63)}[ln] }
    __shared__ __half2 s_Qh[32][64];                   // 8 KB
    __shared__ float s_tanh[2048];                     // 8 KB

    const int tid  = threadIdx.x;
    const int lane = tid & 63;

    for (int i = tid; i < 2048; i += 256)              // tanh((i-1024)/256)
        s_tanh[i] = tanhf((float)(i - 1024) * 0.00390625f);

    for (int idx = tid; idx < 32 * 64; idx += 256) {
        const int k   = idx >> 6;
        const int ln  = idx & 63;
        const int sel = ln >> 5;
        const int j   = (ln + k) & 63;
        const float wo = (sel ? Wcv : Wca)[j];
        const float wd = ((j < 32) ? Wca : Wcv)[ln];
        s_Qh[k][ln] = __floats2half2_rn(wo, wd);
    }
    __syncthreads();

    const int sel = lane >> 5;                         // 0: audio, 1: visual
    const float* __restrict__ fbase = sel ? f2 : f1;
    const float* __restrict__ tb = s_tanh;
    const __half2* __restrict__ Qp = &s_Qh[0][lane];   // step k at Qp[k*64]
    const int col = lane & 31;

    const float w0  = (sel ? Wcv : Wca)[lane];         // k=0 (diagonal), f32 exact
    const float w32 = (sel ? Wcv : Wca)[lane ^ 32];    // k=32
    const int idx31 = ((lane + 31) & 63) << 2;         // bpermute byte indices
    const int idx32 = (lane ^ 32) << 2;

    const int gw     = (blockIdx.x * 256 + tid) >> 6;
    const int stride = (gridDim.x << 2) * 2;           // 2 samples per wave/iter

    int b = gw * 2;
    if (b >= B) return;                                // wave-uniform
    float xA = fbase[b * 32 + col];
    float xB = (b + 1 < B) ? fbase[(b + 1) * 32 + col] : 0.0f;

    while (b < B) {
        const int bn = b + stride;
        float xnA = 0.0f, xnB = 0.0f;
        if (bn < B) {                                  // prefetch next pair
            xnA = fbase[bn * 32 + col];
            if (bn + 1 < B) xnB = fbase[(bn + 1) * 32 + col];
        }

        const float xs32A = xA * 32.0f;                // A: LUT index scale
        const float xcB   = xB * C;                    // B: exp2 arg scale
        float aA = __int_as_float(                     // raw x_{(r+31)&63}
            __builtin_amdgcn_ds_bpermute(idx31, __float_as_int(xA)));
        float aB = __int_as_float(
            __builtin_amdgcn_ds_bpermute(idx31, __float_as_int(xB)));
        const float a32A = __int_as_float(             // raw x_{r^32}
            __builtin_amdgcn_ds_bpermute(idx32, __float_as_int(xA)));
        const float a32B = __int_as_float(
            __builtin_amdgcn_ds_bpermute(idx32, __float_as_int(xB)));

        // k=0 diagonal + k=32 (both lanes own-row), per sample
        float own0A = tanh_lut(tb, xs32A, xA)   * w0;
        float own0B = tanh_sig(xcB, xB)         * w0;
        float own1A = tanh_lut(tb, xs32A, a32A) * w32;
        float own1B = tanh_sig(xcB, a32B)       * w32;

        float tA = 0.0f, tB = 0.0f;                    // traveling mirror accs
        #pragma unroll
        for (int k = 31; k >= 1; --k) {
            const float2 w2 = __half22float2(Qp[k * 64]);  // ds_read_b32 + 2 cvt
            const float pA = tanh_lut(tb, xs32A, aA);      // DS pipe
            const float pB = tanh_sig(xcB, aB);            // trans pipe
            if (k & 1) { own0A = fmaf(pA, w2.x, own0A); own0B = fmaf(pB, w2.x, own0B); }
            else       { own1A = fmaf(pA, w2.x, own1A); own1B = fmaf(pB, w2.x, own1B); }
            tA = wave_ror1_f32(fmaf(pA, w2.y, tA));
            aA = wave_ror1_f32(aA);
            tB = wave_ror1_f32(fmaf(pB, w2.y, tB));
            aB = wave_ror1_f32(aB);
        }
        // after the k=1 iteration each deposit has had exactly k rotations

        const float hA = fmaxf(xA + own0A + own1A + tA, 0.0f) * 0.1f;
        const float hB = fmaxf(xB + own0B + own1B + tB, 0.0f) * 0.1f;
        out[b * 64 + lane] = hA;
        if (b + 1 < B) out[(b + 1) * 64 + lane] = hB;

        b = bn;
        xA = xnA;
        xB = xnB;
    }
}

extern "C" void kernel_launch(void* const* d_in, const int* in_sizes, int n_in,
                              void* d_out, int out_size, void* d_ws, size_t ws_size,
                              hipStream_t stream) {
    const float* f1  = (const float*)d_in[0];
    const float* f2  = (const float*)d_in[1];
    const float* Wca = (const float*)d_in[2];
    const float* Wcv = (const float*)d_in[3];
    float* out = (float*)d_out;

    const int B = in_sizes[0] / 32;
    const int pairs = (B + 1) / 2;
    int blocks = (pairs + 3) / 4;       // 4 waves/block, 1 pair/wave minimum
    if (blocks > 2048) blocks = 2048;   // 8 blocks/CU (16.4 KB LDS) = 32 waves/CU
    if (blocks < 1) blocks = 1;

    cam_kernel<<<blocks, 256, 0, stream>>>(f1, f2, Wca, Wcv, out, B);
}

// Round 14
// 129.580 us; speedup vs baseline: 1.0259x; 1.0259x over previous
//
#include <hip/hip_runtime.h>
#include <math.h>

// CAM_43344809951340: per-sample symmetric outer-product tanh attention.
// H_row[r] = 0.1*relu( sum_j tanh(x_r * av_j / 8) * W_{row_r}[j] + x_r )
//
// Validated diagonal walk (R5-R13, absmax ~2e-3): step k=31..1, lane r
// computes p = tanh(x_r * x_j / 8), j=(r+k)&63, once per unordered pair:
//   own-row:  p * wo_k   (wo_k = W_{sel(r)}[(r+k)&63])
//   mirror:   t = ror1(fma(p, wd_k, t))  (wd_k = W_{sel(j)}[r]);
//             WAVE_ROR1 (0x13C, D[i]=S[(i-1)&63]) drifts deposits toward
//             higher lanes; a deposit at step k lands at r+k after k rolls.
// tanh via 2048-pt nearest LDS LUT (R10); BOTH samples use the LUT --
// R13 measured the exp2+rcp path at ~16 cy/step marginal: trans evals are
// ~2x a LUT eval. All-LUT is the fastest validated config (R12, 58us).
//
// R14 change (from the R12 DS-bound model: 97 DS instr/pair x 5.8cy +
// 3.2cy/gather conflicts ~= 148k cy/CU ~= wall): WEIGHTS LEAVE LDS.
//   wo_k(r) = W_sel[(r+k)&63] is a lane-rotation of the fixed vectors
//   Va_r=Wca[r], Vv_r=Wcv[r]: pre-rotate both by 31 (one bpermute each),
//   then ror1 per step next to the t/a chains; select via lane-const sel.
//   wd_k(r) = (j<32?Wca:Wcv)[r]: rotating 0/1 mask m -> wd=fma(m,d,wcv).
// DS 97->66 instr/pair (-31 reads, ~-35k cy/CU); +5 VALU/step lands on
// the ~40%-idle VALU pipe. LDS shrinks to the 8 KB table; weights exact f32.
// __launch_bounds__(256,4): 128-VGPR budget (R7/R9/R11: tighter caps
// spill the loop to scratch); occupancy follows actual VGPR (~68).

__device__ __forceinline__ float wave_ror1_f32(float v) {
    // D[i] = S[(i-1) & 63] — values move toward higher lanes
    return __int_as_float(__builtin_amdgcn_update_dpp(
        __float_as_int(v), __float_as_int(v), 0x13C, 0xF, 0xF, false));
}

// tanh(x * a / 8) by nearest lookup; xs32 = 32*x so idx = 256*u + 1024.
__device__ __forceinline__ float tanh_lut(const float* __restrict__ tb,
                                          float xs32, float a) {
    float idxf = fmaf(xs32, a, 1024.5f);               // +0.5: round via trunc
    idxf = __builtin_amdgcn_fmed3f(idxf, 0.0f, 2047.0f);
    return tb[(int)idxf];
}

__global__ __launch_bounds__(256, 4) void cam_kernel(
    const float* __restrict__ f1,
    const float* __restrict__ f2,
    const float* __restrict__ Wca,
    const float* __restrict__ Wcv,
    float* __restrict__ out,
    int B)
{
    __shared__ float s_tanh[2048];                     // 8 KB (only LDS)

    const int tid  = threadIdx.x;
    const int lane = tid & 63;

    for (int i = tid; i < 2048; i += 256)              // tanh((i-1024)/256)
        s_tanh[i] = tanhf((float)(i - 1024) * 0.00390625f);
    __syncthreads();

    const int sel = lane >> 5;                         // 0: audio, 1: visual
    const float* __restrict__ fbase = sel ? f2 : f1;
    const float* __restrict__ tb = s_tanh;
    const int col = lane & 31;

    // lane-constant weights
    const float wcaR = Wca[lane];                      // W_ca[r]
    const float wcvR = Wcv[lane];                      // W_cv[r]
    const float dR   = wcaR - wcvR;                    // for wd = fma(m,d,wcv)
    const float w0   = sel ? wcvR : wcaR;              // k=0 (diagonal)
    const float w32  = (sel ? Wcv : Wca)[lane ^ 32];   // k=32

    const int idx31 = ((lane + 31) & 63) << 2;         // bpermute byte indices
    const int idx32 = (lane ^ 32) << 2;

    // rotating weight bases, pre-rotated to the k=31 state (rol^31)
    const float Va31 = __int_as_float(
        __builtin_amdgcn_ds_bpermute(idx31, __float_as_int(wcaR)));
    const float Vv31 = __int_as_float(
        __builtin_amdgcn_ds_bpermute(idx31, __float_as_int(wcvR)));
    const float M31 = __int_as_float(
        __builtin_amdgcn_ds_bpermute(idx31,
            __float_as_int((lane < 32) ? 1.0f : 0.0f)));

    const int gw     = (blockIdx.x * 256 + tid) >> 6;
    const int stride = (gridDim.x << 2) * 2;           // 2 samples per wave/iter

    int b = gw * 2;
    if (b >= B) return;                                // wave-uniform
    float xA = fbase[b * 32 + col];
    float xB = (b + 1 < B) ? fbase[(b + 1) * 32 + col] : 0.0f;

    while (b < B) {
        const int bn = b + stride;
        float xnA = 0.0f, xnB = 0.0f;
        if (bn < B) {                                  // prefetch next pair
            xnA = fbase[bn * 32 + col];
            if (bn + 1 < B) xnB = fbase[(bn + 1) * 32 + col];
        }

        const float xs32A = xA * 32.0f;                // LUT index scales
        const float xs32B = xB * 32.0f;
        float aA = __int_as_float(                     // raw x_{(r+31)&63}
            __builtin_amdgcn_ds_bpermute(idx31, __float_as_int(xA)));
        float aB = __int_as_float(
            __builtin_amdgcn_ds_bpermute(idx31, __float_as_int(xB)));
        const float a32A = __int_as_float(             // raw x_{r^32}
            __builtin_amdgcn_ds_bpermute(idx32, __float_as_int(xA)));
        const float a32B = __int_as_float(
            __builtin_amdgcn_ds_bpermute(idx32, __float_as_int(xB)));

        // k=0 diagonal + k=32 (both lanes own-row), per sample
        float own0A = tanh_lut(tb, xs32A, xA)   * w0;
        float own0B = tanh_lut(tb, xs32B, xB)   * w0;
        float own1A = tanh_lut(tb, xs32A, a32A) * w32;
        float own1B = tanh_lut(tb, xs32B, a32B) * w32;

        float va = Va31, vv = Vv31, m = M31;           // weight rotation state
        float tA = 0.0f, tB = 0.0f;                    // traveling mirror accs
        #pragma unroll
        for (int k = 31; k >= 1; --k) {
            const float wo = sel ? vv : va;            // W_sel[(r+k)&63]
            const float wd = fmaf(m, dR, wcvR);        // W_{half(j)}[r]
            const float pA = tanh_lut(tb, xs32A, aA);
            const float pB = tanh_lut(tb, xs32B, aB);
            if (k & 1) { own0A = fmaf(pA, wo, own0A); own0B = fmaf(pB, wo, own0B); }
            else       { own1A = fmaf(pA, wo, own1A); own1B = fmaf(pB, wo, own1B); }
            tA = wave_ror1_f32(fmaf(pA, wd, tA));
            aA = wave_ror1_f32(aA);
            tB = wave_ror1_f32(fmaf(pB, wd, tB));
            aB = wave_ror1_f32(aB);
            va = wave_ror1_f32(va);                    // rol^k -> rol^(k-1)
            vv = wave_ror1_f32(vv);
            m  = wave_ror1_f32(m);
        }
        // after the k=1 iteration each deposit has had exactly k rotations

        const float hA = fmaxf(xA + own0A + own1A + tA, 0.0f) * 0.1f;
        const float hB = fmaxf(xB + own0B + own1B + tB, 0.0f) * 0.1f;
        out[b * 64 + lane] = hA;
        if (b + 1 < B) out[(b + 1) * 64 + lane] = hB;

        b = bn;
        xA = xnA;
        xB = xnB;
    }
}

extern "C" void kernel_launch(void* const* d_in, const int* in_sizes, int n_in,
                              void* d_out, int out_size, void* d_ws, size_t ws_size,
                              hipStream_t stream) {
    const float* f1  = (const float*)d_in[0];
    const float* f2  = (const float*)d_in[1];
    const float* Wca = (const float*)d_in[2];
    const float* Wcv = (const float*)d_in[3];
    float* out = (float*)d_out;

    const int B = in_sizes[0] / 32;
    const int pairs = (B + 1) / 2;
    int blocks = (pairs + 3) / 4;       // 4 waves/block, 1 pair/wave minimum
    if (blocks > 2048) blocks = 2048;   // up to 8 blocks/CU (8.2 KB LDS)
    if (blocks < 1) blocks = 1;

    cam_kernel<<<blocks, 256, 0, stream>>>(f1, f2, Wca, Wcv, out, B);
}